// Round 5
// baseline (39.274 us; speedup 1.0000x reference)
//
#include <hip/hip_runtime.h>
#include <math.h>

#define BATCH   256
#define IN_F    2048
#define OUT_F   256
#define KD      8
#define NCOL    2048    /* OUT_F*KD */
#define OSTRIDE 2304    /* IN_F + OUT_F */
#define LOG2E   1.4426950408889634f

typedef float    f32x4  __attribute__((ext_vector_type(4)));
typedef short    bf16x8 __attribute__((ext_vector_type(8)));
typedef _Float16 h16x2  __attribute__((ext_vector_type(2)));
typedef __fp16   fp16x2 __attribute__((ext_vector_type(2)));
typedef unsigned short u16;
typedef unsigned int   u32;

// ws layout:
//   [0, 8MB)   Mp[4 kc][256 o][256 j][8 k] f32   (split-K partials)
//   [8, 16MB)  Wt bf16 tiled [nt(128)][kc(256)][n16(16)][8]
//   [16,17MB)  Xb bf16 tiled [rt(16)][kc(256)][r16(16)][8] (pre-scaled by log2e)
#define WT_OFF (8u << 20)
#define XB_OFF (16u << 20)
#define CHUNK  524288   /* floats per Mp partial (2MB) */

__device__ __forceinline__ u16 f2bf(float f) {
    unsigned u = __builtin_bit_cast(unsigned, f);
    u += 0x7fff + ((u >> 16) & 1);              // RNE
    return (u16)(u >> 16);
}

// ---------------------------------------------------------------------------
// Fused prep: T transpose+convert (tiled), X convert (tiled, *log2e), X copy.
// ---------------------------------------------------------------------------
__global__ __launch_bounds__(256)
void k_prep(const float* __restrict__ X, const float* __restrict__ T,
            u16* __restrict__ Wt, u16* __restrict__ Xb,
            float* __restrict__ out) {
    const int b = blockIdx.x, t = threadIdx.x;
    if (b < 256) {
        const int n  = (b & 7) * 256 + t;
        const int kg = b >> 3;
        const int nt = n >> 4, n16 = n & 15;
#pragma unroll
        for (int kc = 0; kc < 8; ++kc) {
            const int kb = kg * 64 + kc * 8;
            u16 h[8];
#pragma unroll
            for (int r = 0; r < 8; ++r)
                h[r] = f2bf(T[(size_t)(kb + r) * NCOL + n]);
            *(float4*)(Wt + ((size_t)(nt * 256 + kg * 8 + kc) * 16 + n16) * 8) =
                *(float4*)h;
        }
    } else if (b < 512) {
        const int g   = b - 256;
        const int rt  = g >> 4;
        const int kc  = (g & 15) * 16 + (t & 15);
        const int r16 = t >> 4;
        const float* src = X + (size_t)(rt * 16 + r16) * IN_F + kc * 8;
        float4 v0 = *(const float4*)src;
        float4 v1 = *(const float4*)(src + 4);
        u16 h[8] = {f2bf(v0.x * LOG2E), f2bf(v0.y * LOG2E),
                    f2bf(v0.z * LOG2E), f2bf(v0.w * LOG2E),
                    f2bf(v1.x * LOG2E), f2bf(v1.y * LOG2E),
                    f2bf(v1.z * LOG2E), f2bf(v1.w * LOG2E)};
        *(float4*)(Xb + ((size_t)(rt * 256 + kc) * 16 + r16) * 8) = *(float4*)h;
    } else {
        const int idx = (b - 512) * 256 + t;
        const int e = idx << 2;
        const int r = e >> 11, c = e & (IN_F - 1);
        *(float4*)(out + (size_t)r * OSTRIDE + c) = *(const float4*)(X + e);
    }
}

// ---------------------------------------------------------------------------
// Split-K MFMA GEMM, no LDS/barriers. Wave = 32x32 output tile, K-chunk 512.
// 256 blocks x 8 waves = 2048 wave-jobs = (R:8) x (C:64) x (kc:4).
// Block: fixed R, 4 C-tiles, 2 kc -> A-streams shared by 4 waves (L1 dedup).
// bid = R*32 + Cq*2 + kcp keeps same-B blocks on one XCD (bid%8 const).
// Writes partial Mp[kc][o][j][k]; pair kernel sums the 4 partials.
// ---------------------------------------------------------------------------
__global__ __launch_bounds__(512)
void k_gemm(const u16* __restrict__ Xb, const u16* __restrict__ Wt,
            float* __restrict__ Mp) {
    const int t = threadIdx.x, l = t & 63, w = t >> 6;
    const int bid = blockIdx.x;
    const int R   = bid >> 5;             // 0..7   (32-row group)
    const int Cq  = (bid & 31) >> 1;      // 0..15  (128-col group)
    const int kcp = bid & 1;
    const int C   = Cq * 4 + (w & 3);     // 0..63  (32-col tile)
    const int kc  = kcp * 2 + (w >> 2);   // 0..3   (K-chunk)

    const int lo = (l >> 4) * 128 + (l & 15) * 8;
    const u16* ap0 = Xb + (size_t)(R * 2) * 32768 + kc * 8192 + lo;
    const u16* ap1 = ap0 + 32768;
    const u16* bp0 = Wt + (size_t)(C * 2) * 32768 + kc * 8192 + lo;
    const u16* bp1 = bp0 + 32768;

    f32x4 c00 = {0.f,0.f,0.f,0.f}, c01 = {0.f,0.f,0.f,0.f};
    f32x4 c10 = {0.f,0.f,0.f,0.f}, c11 = {0.f,0.f,0.f,0.f};

#pragma unroll 4
    for (int s = 0; s < 16; ++s) {
        bf16x8 a0 = *(const bf16x8*)(ap0 + s * 512);
        bf16x8 a1 = *(const bf16x8*)(ap1 + s * 512);
        bf16x8 b0 = *(const bf16x8*)(bp0 + s * 512);
        bf16x8 b1 = *(const bf16x8*)(bp1 + s * 512);
        c00 = __builtin_amdgcn_mfma_f32_16x16x32_bf16(a0, b0, c00, 0, 0, 0);
        c01 = __builtin_amdgcn_mfma_f32_16x16x32_bf16(a0, b1, c01, 0, 0, 0);
        c10 = __builtin_amdgcn_mfma_f32_16x16x32_bf16(a1, b0, c10, 0, 0, 0);
        c11 = __builtin_amdgcn_mfma_f32_16x16x32_bf16(a1, b1, c11, 0, 0, 0);
    }

    float* base = Mp + (size_t)kc * CHUNK;
    const int lq = l >> 4, lm = l & 15;
#define STORE(acc, qi, qj) do { \
        const int c_ = C * 32 + (qj) * 16 + lm; \
        float* d_ = base + (size_t)(((c_ >> 3) * 256) + R * 32 + (qi) * 16 + lq * 4) * 8 + (c_ & 7); \
        d_[0] = acc[0]; d_[8] = acc[1]; d_[16] = acc[2]; d_[24] = acc[3]; \
    } while (0)
    STORE(c00, 0, 0); STORE(c01, 0, 1); STORE(c10, 1, 0); STORE(c11, 1, 1);
#undef STORE
}

// ---------------------------------------------------------------------------
// Pairwise L1-exp2 reduction, packed-f16 math.
// Block = feature o; 512 threads = (i-half h, j). Sums the 4 K-partials
// during staging. Diagonal cancels exactly (identical LDS values -> diff 0).
// ---------------------------------------------------------------------------
__global__ __launch_bounds__(512)
void k_pair(const float* __restrict__ Mp, float* __restrict__ out) {
    __shared__ __align__(16) u32 Msh[BATCH][4];   // 256 rows x 8 f16
    __shared__ float Ps[512];
    const int o = blockIdx.x, t = threadIdx.x;

    {   // stage: sum 4 partial chunks, pack to f16
        const float* p = Mp + (size_t)o * 2048 + t * 4;
        f32x4 v0 = *(const f32x4*)(p);
        f32x4 v1 = *(const f32x4*)(p + CHUNK);
        f32x4 v2 = *(const f32x4*)(p + 2 * CHUNK);
        f32x4 v3 = *(const f32x4*)(p + 3 * CHUNK);
        f32x4 v = (v0 + v1) + (v2 + v3);
        fp16x2 p0 = __builtin_amdgcn_cvt_pkrtz(v[0], v[1]);
        fp16x2 p1 = __builtin_amdgcn_cvt_pkrtz(v[2], v[3]);
        Msh[t >> 1][(t & 1) * 2]     = __builtin_bit_cast(u32, p0);
        Msh[t >> 1][(t & 1) * 2 + 1] = __builtin_bit_cast(u32, p1);
    }
    __syncthreads();

    const int j = t & 255, h = t >> 8;
    uint4 mm = *(const uint4*)Msh[j];
    const h16x2 m0 = __builtin_bit_cast(h16x2, mm.x);
    const h16x2 m1 = __builtin_bit_cast(h16x2, mm.y);
    const h16x2 m2 = __builtin_bit_cast(h16x2, mm.z);
    const h16x2 m3 = __builtin_bit_cast(h16x2, mm.w);

    float acc = 0.f;
    const int i0 = h * 128;
    for (int i = i0; i < i0 + 128; ++i) {
        uint4 uu = *(const uint4*)Msh[i];          // broadcast ds_read_b128
        h16x2 d0 = __builtin_bit_cast(h16x2, uu.x) - m0;
        h16x2 d1 = __builtin_bit_cast(h16x2, uu.y) - m1;
        h16x2 d2 = __builtin_bit_cast(h16x2, uu.z) - m2;
        h16x2 d3 = __builtin_bit_cast(h16x2, uu.w) - m3;
        h16x2 e0 = __builtin_bit_cast(h16x2, __builtin_bit_cast(u32, d0) & 0x7fff7fffu);
        h16x2 e1 = __builtin_bit_cast(h16x2, __builtin_bit_cast(u32, d1) & 0x7fff7fffu);
        h16x2 e2 = __builtin_bit_cast(h16x2, __builtin_bit_cast(u32, d2) & 0x7fff7fffu);
        h16x2 e3 = __builtin_bit_cast(h16x2, __builtin_bit_cast(u32, d3) & 0x7fff7fffu);
        h16x2 s = (e0 + e1) + (e2 + e3);
        float norm = (float)s[0] + (float)s[1];
        acc += exp2f(-norm);
    }
    Ps[t] = acc;
    __syncthreads();
    if (t < 256)
        out[(size_t)t * OSTRIDE + IN_F + o] = Ps[t] + Ps[t + 256] - 1.0f;
}

extern "C" void kernel_launch(void* const* d_in, const int* in_sizes, int n_in,
                              void* d_out, int out_size, void* d_ws, size_t ws_size,
                              hipStream_t stream) {
    const float* x = (const float*)d_in[0];   // [256, 2048]
    const float* T = (const float*)d_in[1];   // [2048][2048] flattened
    float* out = (float*)d_out;               // [256, 2304]
    char* ws = (char*)d_ws;
    float* Mp = (float*)ws;
    u16*  Wt  = (u16*)(ws + WT_OFF);
    u16*  Xb  = (u16*)(ws + XB_OFF);

    k_prep<<<1024, 256, 0, stream>>>(x, T, Wt, Xb, out);
    k_gemm<<<256, 512, 0, stream>>>(Xb, Wt, Mp);
    k_pair<<<256, 512, 0, stream>>>(Mp, out);
}

// Round 6
// 37.637 us; speedup vs baseline: 1.0435x; 1.0435x over previous
//
#include <hip/hip_runtime.h>
#include <math.h>

#define BATCH   256
#define IN_F    2048
#define OUT_F   256
#define NCOL    2048    /* OUT_F*KD */
#define OSTRIDE 2304    /* IN_F + OUT_F */
#define LOG2E   1.4426950408889634f

typedef float    f32x4  __attribute__((ext_vector_type(4)));
typedef short    bf16x8 __attribute__((ext_vector_type(8)));
typedef _Float16 h16x2  __attribute__((ext_vector_type(2)));
typedef __fp16   fp16x2 __attribute__((ext_vector_type(2)));
typedef unsigned short u16;
typedef unsigned int   u32;

// ws layout:
//   [0, 1MB)   Mh f16 [256 o][256 j][8 k]  (GEMM output, pair-staging format)
//   [8, 16MB)  Wt bf16 tiled [nt(128)][kchunk(256)][n16(16)][8]
//   [16,17MB)  Xb bf16 tiled [rt(16)][kchunk(256)][r16(16)][8] (pre-scaled by log2e)
#define WT_OFF (8u << 20)
#define XB_OFF (16u << 20)

__device__ __forceinline__ u16 f2bf(float f) {
    unsigned u = __builtin_bit_cast(unsigned, f);
    u += 0x7fff + ((u >> 16) & 1);              // RNE
    return (u16)(u >> 16);
}

// ---------------------------------------------------------------------------
// Prep: blocks 0..127  = T transpose+convert (thread owns an n-pair, float2)
//       blocks 128..383 = X convert->Xb (tiled, *log2e) + X copy->out
// ---------------------------------------------------------------------------
__global__ __launch_bounds__(256)
void k_prep(const float* __restrict__ X, const float* __restrict__ T,
            u16* __restrict__ Wt, u16* __restrict__ Xb,
            float* __restrict__ out) {
    const int b = blockIdx.x, t = threadIdx.x;
    if (b < 128) {
        const int np = (b & 3) * 256 + t;       // 0..1023
        const int n  = np * 2;
        const int kg = b >> 2;                  // 0..31 (64-k group)
        const int nt = n >> 4, n16 = n & 15;
#pragma unroll
        for (int kc = 0; kc < 8; ++kc) {
            const int kb = kg * 64 + kc * 8;
            u16 h0[8], h1[8];
#pragma unroll
            for (int r = 0; r < 8; ++r) {
                float2 v = *(const float2*)(T + (size_t)(kb + r) * NCOL + n);
                h0[r] = f2bf(v.x);
                h1[r] = f2bf(v.y);
            }
            u16* dst = Wt + ((size_t)(nt * 256 + kg * 8 + kc) * 16 + n16) * 8;
            *(float4*)dst       = *(float4*)h0;
            *(float4*)(dst + 8) = *(float4*)h1;
        }
    } else {
        const int g   = b - 128;                // 0..255
        const int rt  = g >> 4;
        const int kc  = (g & 15) * 16 + (t & 15);
        const int r16 = t >> 4;
        const int row = rt * 16 + r16;
        const float* src = X + (size_t)row * IN_F + kc * 8;
        float4 v0 = *(const float4*)src;
        float4 v1 = *(const float4*)(src + 4);
        u16 h[8] = {f2bf(v0.x * LOG2E), f2bf(v0.y * LOG2E),
                    f2bf(v0.z * LOG2E), f2bf(v0.w * LOG2E),
                    f2bf(v1.x * LOG2E), f2bf(v1.y * LOG2E),
                    f2bf(v1.z * LOG2E), f2bf(v1.w * LOG2E)};
        *(float4*)(Xb + ((size_t)(rt * 256 + kc) * 16 + r16) * 8) = *(float4*)h;
        float* od = out + (size_t)row * OSTRIDE + kc * 8;
        *(float4*)od       = v0;
        *(float4*)(od + 4) = v1;
    }
}

// ---------------------------------------------------------------------------
// MFMA GEMM with in-block split-K reduce. 256 blocks x 8 waves.
// Block = (R: 32-row group 0..7, Cp: 64-col group 0..31); bid = R*32+Cp keeps
// same-B-panel blocks (same Cp) on one XCD (bid%8 = Cp%8).
// Wave w: cw = w&1 (32-col tile), kcw = w>>1 (512-k chunk). 32x32 out/wave,
// 2x2 fragment reuse. Waves reduce over kcw through padded LDS; stores
// Mh[o][j][k] f16 fully coalesced (512 B/wave dwordx2).
// C/D frag: col = l&15, row = (l>>4)*4 + reg  [m89/m91].
// ---------------------------------------------------------------------------
__global__ __launch_bounds__(512)
void k_gemm(const u16* __restrict__ Xb, const u16* __restrict__ Wt,
            u16* __restrict__ Mh) {
    __shared__ float L[4][64][33];     // 33.8 KB, +1 pad vs 32
    const int t = threadIdx.x, l = t & 63, w = t >> 6;
    const int bid = blockIdx.x;
    const int R  = bid >> 5;           // 0..7
    const int Cp = bid & 31;           // 0..31
    const int cw = w & 1, kcw = w >> 1;
    const int C  = Cp * 2 + cw;        // 0..63 (32-col tile)

    const int lo = (l >> 4) * 128 + (l & 15) * 8;
    const u16* ap0 = Xb + (size_t)(R * 2) * 32768 + kcw * 8192 + lo;
    const u16* ap1 = ap0 + 32768;
    const u16* bp0 = Wt + (size_t)(C * 2) * 32768 + kcw * 8192 + lo;
    const u16* bp1 = bp0 + 32768;

    f32x4 c00 = {0.f,0.f,0.f,0.f}, c01 = {0.f,0.f,0.f,0.f};
    f32x4 c10 = {0.f,0.f,0.f,0.f}, c11 = {0.f,0.f,0.f,0.f};

#pragma unroll 4
    for (int s = 0; s < 16; ++s) {
        bf16x8 a0 = *(const bf16x8*)(ap0 + s * 512);
        bf16x8 a1 = *(const bf16x8*)(ap1 + s * 512);
        bf16x8 b0 = *(const bf16x8*)(bp0 + s * 512);
        bf16x8 b1 = *(const bf16x8*)(bp1 + s * 512);
        c00 = __builtin_amdgcn_mfma_f32_16x16x32_bf16(a0, b0, c00, 0, 0, 0);
        c01 = __builtin_amdgcn_mfma_f32_16x16x32_bf16(a0, b1, c01, 0, 0, 0);
        c10 = __builtin_amdgcn_mfma_f32_16x16x32_bf16(a1, b0, c10, 0, 0, 0);
        c11 = __builtin_amdgcn_mfma_f32_16x16x32_bf16(a1, b1, c11, 0, 0, 0);
    }

    const int lq = l >> 4, lm = l & 15;
#define PUT(acc, qi, qj) do { \
        _Pragma("unroll") \
        for (int r = 0; r < 4; ++r) \
            L[kcw][cw * 32 + (qj) * 16 + lm][(qi) * 16 + lq * 4 + r] = acc[r]; \
    } while (0)
    PUT(c00, 0, 0); PUT(c01, 0, 1); PUT(c10, 1, 0); PUT(c11, 1, 1);
#undef PUT
    __syncthreads();

    // reduce over kcw + convert + coalesced store
    const int ol = t >> 6;             // 0..7  (local o)
    const int jl = (t & 63) >> 1;      // 0..31 (local j)
    const int k0 = (t & 1) * 4;        // 0 or 4
    float v[4];
#pragma unroll
    for (int i = 0; i < 4; ++i) {
        const int c = ol * 8 + k0 + i;
        v[i] = (L[0][c][jl] + L[1][c][jl]) + (L[2][c][jl] + L[3][c][jl]);
    }
    fp16x2 p0 = __builtin_amdgcn_cvt_pkrtz(v[0], v[1]);
    fp16x2 p1 = __builtin_amdgcn_cvt_pkrtz(v[2], v[3]);
    uint2 pk = {__builtin_bit_cast(u32, p0), __builtin_bit_cast(u32, p1)};
    *(uint2*)(Mh + ((size_t)(Cp * 8 + ol) * 256 + R * 32 + jl) * 8 + k0) = pk;
}

// ---------------------------------------------------------------------------
// Pairwise L1-exp2, packed f16. Block = feature o; 512 threads = (half h, j).
// Staging is a single coalesced 4 KB load (Mh already in [j][8k] rows).
// Diagonal cancels exactly (identical values -> diff 0 -> exp2(0)=1 vs -1).
// ---------------------------------------------------------------------------
__global__ __launch_bounds__(512)
void k_pair(const u16* __restrict__ Mh, float* __restrict__ out) {
    __shared__ __align__(16) uint4 Msh[BATCH];    // 4 KB
    __shared__ float Ps[512];
    const int o = blockIdx.x, t = threadIdx.x;

    ((uint2*)Msh)[t] = ((const uint2*)(Mh + (size_t)o * 2048))[t];
    __syncthreads();

    const int j = t & 255, h = t >> 8;
    uint4 mm = Msh[j];
    const h16x2 m0 = __builtin_bit_cast(h16x2, mm.x);
    const h16x2 m1 = __builtin_bit_cast(h16x2, mm.y);
    const h16x2 m2 = __builtin_bit_cast(h16x2, mm.z);
    const h16x2 m3 = __builtin_bit_cast(h16x2, mm.w);

    float acc = 0.f;
    const int i0 = h * 128;
    for (int i = i0; i < i0 + 128; ++i) {
        uint4 uu = Msh[i];                        // broadcast ds_read_b128
        h16x2 d0 = __builtin_bit_cast(h16x2, uu.x) - m0;
        h16x2 d1 = __builtin_bit_cast(h16x2, uu.y) - m1;
        h16x2 d2 = __builtin_bit_cast(h16x2, uu.z) - m2;
        h16x2 d3 = __builtin_bit_cast(h16x2, uu.w) - m3;
        h16x2 e0 = __builtin_bit_cast(h16x2, __builtin_bit_cast(u32, d0) & 0x7fff7fffu);
        h16x2 e1 = __builtin_bit_cast(h16x2, __builtin_bit_cast(u32, d1) & 0x7fff7fffu);
        h16x2 e2 = __builtin_bit_cast(h16x2, __builtin_bit_cast(u32, d2) & 0x7fff7fffu);
        h16x2 e3 = __builtin_bit_cast(h16x2, __builtin_bit_cast(u32, d3) & 0x7fff7fffu);
        h16x2 s = (e0 + e1) + (e2 + e3);
        float norm = (float)s[0] + (float)s[1];
        acc += exp2f(-norm);
    }
    Ps[t] = acc;
    __syncthreads();
    if (t < 256)
        out[(size_t)t * OSTRIDE + IN_F + o] = Ps[t] + Ps[t + 256] - 1.0f;
}

extern "C" void kernel_launch(void* const* d_in, const int* in_sizes, int n_in,
                              void* d_out, int out_size, void* d_ws, size_t ws_size,
                              hipStream_t stream) {
    const float* x = (const float*)d_in[0];   // [256, 2048]
    const float* T = (const float*)d_in[1];   // [2048][2048] flattened
    float* out = (float*)d_out;               // [256, 2304]
    char* ws = (char*)d_ws;
    u16* Mh = (u16*)ws;
    u16* Wt = (u16*)(ws + WT_OFF);
    u16* Xb = (u16*)(ws + XB_OFF);

    k_prep<<<384, 256, 0, stream>>>(x, T, Wt, Xb, out);
    k_gemm<<<256, 512, 0, stream>>>(Xb, Wt, Mh);
    k_pair<<<256, 512, 0, stream>>>(Mh, out);
}